// Round 1
// baseline (159.655 us; speedup 1.0000x reference)
//
#include <hip/hip_runtime.h>

#define LSEQ 384
#define NROWS 1536      // B*L
#define FDIM 640
#define HDIM 128
#define PART 196608     // 1536*128

// ws layout (float indices) — keep legacy offsets (regions 0..11 now unused)
#define WS_FI  (12*PART)         // final fi
#define WS_FJ  (13*PART)         // final fj
#define WS_QC  (14*PART)
#define WS_FLAG (WS_QC + NROWS)  // int[1536]

// out layout (float indices)
#define OUT_PC    0
#define OUT_TC    4608
#define OUT_NET   9216
#define OUT_POT   10752
#define OUT_MASK  12288
#define OUT_EN    602112

typedef float f4 __attribute__((ext_vector_type(4)));

__device__ __forceinline__ void gl16(const float* g, float* l) {
    __builtin_amdgcn_global_load_lds((const __attribute__((address_space(1))) float*)g,
                                     (__attribute__((address_space(3))) float*)l, 16, 0, 0);
}

// =========== Kernel 1: fused GEMM (X@W -> 128 wide) + row epilogue ===========
// grid (192, 3): bx = m-tile of 8 rows; mat: 0=H1(+epilogue), 1=fi, 2=fj.
// 128 threads: thread tile 2 rows x 4 cols (rg = t>>5 in 0..3, cg = t&31).
// K loop: 20 tiles of BK=32, double-buffered LDS via global_load_lds (16B).
__global__ __launch_bounds__(128) void k_fused(const float* __restrict__ X,
                                               const float* __restrict__ W1,
                                               const float* __restrict__ sW1,
                                               const float* __restrict__ b1,
                                               const float* __restrict__ gam,
                                               const float* __restrict__ bet,
                                               const float* __restrict__ rmean,
                                               const float* __restrict__ rvar,
                                               const float* __restrict__ W2,
                                               const float* __restrict__ b2,
                                               const float* __restrict__ W3,
                                               const float* __restrict__ b3,
                                               const int* __restrict__ seq,
                                               float* __restrict__ ws,
                                               float* __restrict__ out) {
    __shared__ __align__(16) float As[2][8][32];     // [buf][m][k]  1KB each
    __shared__ __align__(16) float Bs[2][32][128];   // [buf][k][n] 16KB each

    const int t   = threadIdx.x;
    const int bx  = blockIdx.x;     // 0..191
    const int mat = blockIdx.y;     // 0..2
    const int m0  = bx * 8;
    const float* W = (mat == 0) ? W1 : (mat == 1 ? sW1 : sW1 + FDIM * HDIM);

    if (mat == 0 && bx == 0 && t < 4) out[OUT_EN + t] = 0.0f;   // k2 atomicAdds later

    const int lane = t & 63, wv = t >> 6;
    const int rg = t >> 5, cg = t & 31;

    // async stage of K-tile kt into buffer buf
    auto stage = [&](int buf, int kt) {
        const int k0 = kt * 32;
        // B tile: 32x128 floats, CONTIGUOUS at W + k0*128. 16 chunks of 1024B.
        const float* wsrc = W + (long)k0 * HDIM;
        float* bdst = &Bs[buf][0][0];
#pragma unroll
        for (int c = 0; c < 8; c++) {
            const int idx = c * 2 + wv;                 // wave-uniform
            gl16(wsrc + idx * 256 + lane * 4, bdst + idx * 256);
        }
        // A tile: 8 rows x 32 floats (row stride FDIM). One 1024B inst, wave 0.
        if (wv == 0)
            gl16(X + (long)(m0 + (lane >> 3)) * FDIM + k0 + (lane & 7) * 4,
                 &As[buf][0][0]);
    };

    f4 acc0 = {0.f, 0.f, 0.f, 0.f};
    f4 acc1 = {0.f, 0.f, 0.f, 0.f};

    stage(0, 0);
    __syncthreads();            // implicit vmcnt(0) drain: tile 0 resident

#pragma unroll 2
    for (int kt = 0; kt < 20; kt++) {
        const int buf = kt & 1;
        if (kt < 19) stage(buf ^ 1, kt + 1);    // async, in flight over compute

        const float* Ab = &As[buf][0][0];
        const float* Bb = &Bs[buf][0][0];
#pragma unroll
        for (int k4 = 0; k4 < 32; k4 += 4) {
            f4 a0 = *(const f4*)&Ab[(rg * 2 + 0) * 32 + k4];   // 2-addr broadcast
            f4 a1 = *(const f4*)&Ab[(rg * 2 + 1) * 32 + k4];
#pragma unroll
            for (int kk = 0; kk < 4; kk++) {
                f4 bv = *(const f4*)&Bb[(k4 + kk) * 128 + cg * 4]; // consecutive b128
                acc0 += a0[kk] * bv;
                acc1 += a1[kk] * bv;
            }
        }
        __syncthreads();   // waves done reading buf; stage into buf^1 drained
    }

    if (mat != 0) {
        float* O = ws + (mat == 1 ? WS_FI : WS_FJ);
        *(f4*)&O[(long)(m0 + rg * 2 + 0) * HDIM + cg * 4] = acc0;
        *(f4*)&O[(long)(m0 + rg * 2 + 1) * HDIM + cg * 4] = acc1;
        return;
    }

    // ---- H1 epilogue, fully in-block (h never hits global memory) ----
    float* hs = (float*)Bs;                       // reuse: 8x128 floats
    *(f4*)&hs[(rg * 2 + 0) * 128 + cg * 4] = acc0;
    *(f4*)&hs[(rg * 2 + 1) * 128 + cg * 4] = acc1;
    __syncthreads();

    // per-lane channel constants (row-invariant)
    const float b1v0 = b1[lane],      b1v1 = b1[lane + 64];
    const float sc0  = gam[lane]      / sqrtf(rvar[lane] + 1e-5f);
    const float sc1  = gam[lane + 64] / sqrtf(rvar[lane + 64] + 1e-5f);
    const float rm0  = rmean[lane],   rm1  = rmean[lane + 64];
    const float bt0  = bet[lane],     bt1  = bet[lane + 64];

    float h0[4], h1[4];
#pragma unroll
    for (int r = 0; r < 4; r++) {
        const int row = wv * 4 + r;
        float v0 = fmaxf(hs[row * 128 + lane] + b1v0, 0.0f);
        float v1 = fmaxf(hs[row * 128 + 64 + lane] + b1v1, 0.0f);
        h0[r] = (v0 - rm0) * sc0 + bt0;
        h1[r] = (v1 - rm1) * sc1 + bt1;
    }

    const float b2v = b2[lane];
    float a2[4] = {b2v, b2v, b2v, b2v};
#pragma unroll
    for (int cc = 0; cc < 64; cc++) {
        const float wv0 = W2[cc * 64 + lane];
        const float wv1 = W2[(cc + 64) * 64 + lane];
#pragma unroll
        for (int r = 0; r < 4; r++) {
            float hv0 = __uint_as_float(__builtin_amdgcn_readlane(__float_as_uint(h0[r]), cc));
            float hv1 = __uint_as_float(__builtin_amdgcn_readlane(__float_as_uint(h1[r]), cc));
            a2[r] = fmaf(hv0, wv0, a2[r]);
            a2[r] = fmaf(hv1, wv1, a2[r]);
        }
    }

    const float w30 = W3[lane * 3 + 0], w31 = W3[lane * 3 + 1], w32 = W3[lane * 3 + 2];
#pragma unroll
    for (int r = 0; r < 4; r++) {
        float h2 = fmaxf(a2[r], 0.0f);
        float x0 = h2 * w30, x1 = h2 * w31, x2 = h2 * w32;
#pragma unroll
        for (int o = 32; o > 0; o >>= 1) {
            x0 += __shfl_xor(x0, o, 64);
            x1 += __shfl_xor(x1, o, 64);
            x2 += __shfl_xor(x2, o, 64);
        }
        if (lane == 0) {
            const int row = m0 + wv * 4 + r;
            float l0 = x0 + b3[0], l1 = x1 + b3[1], l2 = x2 + b3[2];
            float m = fmaxf(l0, fmaxf(l1, l2));
            float e0 = expf(l0 - m), e1 = expf(l1 - m), e2 = expf(l2 - m);
            float s = e0 + e1 + e2;
            float pc0 = e0 / s, pc1 = e1 / s, pc2 = e2 / s;
            out[OUT_PC + row * 3 + 0] = pc0;
            out[OUT_PC + row * 3 + 1] = pc1;
            out[OUT_PC + row * 3 + 2] = pc2;
            float net = pc0 - pc1;
            out[OUT_NET + row] = net;
            ws[WS_QC + row] = net;
            ((int*)(ws + WS_FLAG))[row] = (pc0 > pc2 ? 1 : 0) | (pc1 > pc2 ? 2 : 0);
            int sid = seq[row];
            float c0 = (sid == 6 || sid == 8 || sid == 14) ? 1.0f : 0.0f;
            float c1 = (sid == 2 || sid == 3) ? 1.0f : 0.0f;
            out[OUT_TC + row * 3 + 0] = c0;
            out[OUT_TC + row * 3 + 1] = c1;
            out[OUT_TC + row * 3 + 2] = (c0 == 0.0f && c1 == 0.0f) ? 1.0f : 0.0f;
        }
    }
}

// =========== Kernel 2: conv + pair sweep + inline candidate MLP ===========
__device__ __forceinline__ float mlp_eval(const float* __restrict__ fi, const float* __restrict__ fj,
                                          int gi, int gj, float D,
                                          float dv0, float dv1, float sb0, float sb1v,
                                          float b2v, float w3l, const float* w2s, int lane) {
    float fi0 = fi[(long)gi * 128 + lane];
    float fi1 = fi[(long)gi * 128 + 64 + lane];
    float fj0 = fj[(long)gj * 128 + lane];
    float fj1 = fj[(long)gj * 128 + 64 + lane];
    float h0 = fmaxf(fi0 + fj0 + D * dv0 + sb0, 0.0f);
    float h1 = fmaxf(fi1 + fj1 + D * dv1 + sb1v, 0.0f);
    float a0 = 0.0f, a1 = 0.0f;
#pragma unroll
    for (int cc = 0; cc < 64; cc++) {
        float hv0 = __uint_as_float(__builtin_amdgcn_readlane(__float_as_uint(h0), cc));
        float hv1 = __uint_as_float(__builtin_amdgcn_readlane(__float_as_uint(h1), cc));
        a0 = fmaf(hv0, w2s[cc * 64 + lane], a0);
        a1 = fmaf(hv1, w2s[(cc + 64) * 64 + lane], a1);
    }
    float x = fmaxf(a0 + a1 + b2v, 0.0f) * w3l;
#pragma unroll
    for (int o = 32; o > 0; o >>= 1) x += __shfl_xor(x, o, 64);
    return x;
}

__global__ __launch_bounds__(256) void k2(const float* __restrict__ S,
                                          const float* __restrict__ ws,
                                          const float* __restrict__ sW1,
                                          const float* __restrict__ sb1,
                                          const float* __restrict__ sW2,
                                          const float* __restrict__ sb2,
                                          const float* __restrict__ sW3,
                                          const float* __restrict__ sb3,
                                          const float* __restrict__ c1w, const float* __restrict__ c1b,
                                          const float* __restrict__ c2w, const float* __restrict__ c2b,
                                          const float* __restrict__ c3w, const float* __restrict__ c3b,
                                          float* __restrict__ out) {
    __shared__ char smem[40960];
    const int t = threadIdx.x;
    const int bi = blockIdx.x;

    if (bi < 4) {
        float* p0 = (float*)smem;
        float* p1 = p0 + 388;
        float* p2 = p1 + 16 * 386;
        const int b = bi;
        for (int j = t; j < LSEQ; j += 256) p0[j + 2] = out[OUT_NET + b * LSEQ + j];
        if (t < 2) { p0[t] = 0.0f; p0[LSEQ + 2 + t] = 0.0f; }
        if (t < 16) { p1[t * 386] = 0.0f; p1[t * 386 + 385] = 0.0f; }
        if (t < 8)  { p2[t * 386] = 0.0f; p2[t * 386 + 385] = 0.0f; }
        __syncthreads();
        for (int pos = t; pos < LSEQ; pos += 256) {
#pragma unroll
            for (int o = 0; o < 16; o++) {
                float acc = c1b[o];
#pragma unroll
                for (int k = 0; k < 5; k++) acc = fmaf(p0[pos + k], c1w[o * 5 + k], acc);
                p1[o * 386 + pos + 1] = fmaxf(acc, 0.0f);
            }
        }
        __syncthreads();
        for (int pos = t; pos < LSEQ; pos += 256) {
#pragma unroll
            for (int o = 0; o < 8; o++) {
                float acc = c2b[o];
                for (int i = 0; i < 16; i++)
#pragma unroll
                    for (int k = 0; k < 3; k++)
                        acc = fmaf(p1[i * 386 + pos + k], c2w[(o * 16 + i) * 3 + k], acc);
                p2[o * 386 + pos + 1] = fmaxf(acc, 0.0f);
            }
        }
        __syncthreads();
        for (int pos = t; pos < LSEQ; pos += 256) {
            float acc = c3b[0];
            for (int i = 0; i < 8; i++)
#pragma unroll
                for (int k = 0; k < 3; k++)
                    acc = fmaf(p2[i * 386 + pos + k], c3w[i * 3 + k], acc);
            out[OUT_POT + b * LSEQ + pos] = acc;
        }
        return;
    }

    float* sx = (float*)smem;
    float* sy = sx + 384;
    float* sz = sy + 384;
    float* sq = sz + 384;
    unsigned int* clist = (unsigned int*)(sz + 768);
    unsigned char* sf = (unsigned char*)(smem + 7680);
    float* red = (float*)(smem + 8064);
    int* cntL = (int*)(smem + 8080);
    float* w2s = (float*)(smem + 8192);

    const float* qc = ws + WS_QC;
    const int* flags = (const int*)(ws + WS_FLAG);
    const float* fi = ws + WS_FI;
    const float* fj = ws + WS_FJ;

    const int row = bi - 4;
    const int b = row / LSEQ;
    const int i = row - b * LSEQ;

    for (int j = t; j < LSEQ; j += 256) {
        int g = b * LSEQ + j;
        sx[j] = S[g * 3 + 0];
        sy[j] = S[g * 3 + 1];
        sz[j] = S[g * 3 + 2];
        sq[j] = qc[g];
        sf[j] = (unsigned char)flags[g];
    }
    if (t == 0) *cntL = 0;
    __syncthreads();

    const float six = sx[i], siy = sy[i], siz = sz[i], qi = sq[i];
    const int fli = sf[i];
    const bool posi = (fli & 1) != 0, negi = (fli & 2) != 0;
    const int lane = t & 63, w = t >> 6;
    float esum = 0.0f;
    float* mrow = out + OUT_MASK + (long)row * LSEQ;

    for (int j = t; j < LSEQ; j += 256) {
        float dx = __fsub_rn(six, sx[j]);
        float dy = __fsub_rn(siy, sy[j]);
        float dz = __fsub_rn(siz, sz[j]);
        float d2 = __fadd_rn(__fadd_rn(__fmul_rn(dx, dx), __fmul_rn(dy, dy)), __fmul_rn(dz, dz));
        d2 = __fadd_rn(d2, 1e-12f);
        float D = __fsqrt_rn(d2);
        mrow[j] = 0.0f;
        if (j > i && D < 15.0f && D > 0.0f) {
            float num = __fmul_rn(__fmul_rn(332.0f, qi), sq[j]);
            float den = __fmul_rn(__fmul_rn(20.0f, D), D);
            esum += __fdiv_rn(num, den);
        }
        int flj = sf[j];
        bool near = (D < 4.0f);
        bool need1 = near && posi && ((flj & 2) != 0);
        bool need2 = near && negi && ((flj & 1) != 0);
        if (need1 || need2) {
            int p = atomicAdd(cntL, 1);
            clist[p] = (unsigned int)j | (need1 ? 512u : 0u) | (need2 ? 1024u : 0u);
        }
    }
#pragma unroll
    for (int o = 32; o > 0; o >>= 1) esum += __shfl_xor(esum, o, 64);
    if (lane == 0) red[w] = esum;
    __syncthreads();
    if (t == 0) {
        float s = red[0] + red[1] + red[2] + red[3];
        atomicAdd(&out[OUT_EN + b], s);
    }

    int nc = *cntL;   // valid: barrier above
    if (nc == 0) return;

    for (int idx = t; idx < 2048; idx += 256)
        ((float4*)w2s)[idx] = ((const float4*)sW2)[idx];
    const float* dvec = sW1 + 1280 * 128;
    const float dv0 = dvec[lane], dv1 = dvec[lane + 64];
    const float sb0 = sb1[lane], sb1v = sb1[lane + 64];
    const float w3l = sW3[lane];
    const float b2v = sb2[lane];
    const float b3v = sb3[0];
    __syncthreads();

    for (int c = w; c < nc; c += 4) {
        unsigned int e = clist[c];
        int j = (int)(e & 511u);
        bool need1 = (e & 512u) != 0, need2 = (e & 1024u) != 0;
        float dx = __fsub_rn(six, sx[j]);
        float dy = __fsub_rn(siy, sy[j]);
        float dz = __fsub_rn(siz, sz[j]);
        float d2 = __fadd_rn(__fadd_rn(__fmul_rn(dx, dx), __fmul_rn(dy, dy)), __fmul_rn(dz, dz));
        d2 = __fadd_rn(d2, 1e-12f);
        float D = __fsqrt_rn(d2);
        int gi = row, gj = b * LSEQ + j;
        bool hit = false;
        if (need1) {
            float x = mlp_eval(fi, fj, gi, gj, D, dv0, dv1, sb0, sb1v, b2v, w3l, w2s, lane);
            hit = (x + b3v) > 0.0f;
        }
        if (!hit && need2) {
            float x = mlp_eval(fi, fj, gj, gi, D, dv0, dv1, sb0, sb1v, b2v, w3l, w2s, lane);
            hit = (x + b3v) > 0.0f;
        }
        if (hit && lane == 0) mrow[j] = 1.0f;
    }
}

extern "C" void kernel_launch(void* const* d_in, const int* in_sizes, int n_in,
                              void* d_out, int out_size, void* d_ws, size_t ws_size,
                              hipStream_t stream) {
    const float* X     = (const float*)d_in[0];
    const int*   seq   = (const int*)d_in[1];
    const float* S     = (const float*)d_in[2];
    const float* W1    = (const float*)d_in[3];
    const float* b1    = (const float*)d_in[4];
    const float* gam   = (const float*)d_in[5];
    const float* bet   = (const float*)d_in[6];
    const float* rmean = (const float*)d_in[7];
    const float* rvar  = (const float*)d_in[8];
    const float* W2    = (const float*)d_in[9];
    const float* b2    = (const float*)d_in[10];
    const float* W3    = (const float*)d_in[11];
    const float* b3    = (const float*)d_in[12];
    const float* sW1   = (const float*)d_in[13];
    const float* sb1   = (const float*)d_in[14];
    const float* sW2   = (const float*)d_in[15];
    const float* sb2   = (const float*)d_in[16];
    const float* sW3   = (const float*)d_in[17];
    const float* sb3   = (const float*)d_in[18];
    const float* c1w   = (const float*)d_in[19];
    const float* c1b   = (const float*)d_in[20];
    const float* c2w   = (const float*)d_in[21];
    const float* c2b   = (const float*)d_in[22];
    const float* c3w   = (const float*)d_in[23];
    const float* c3b   = (const float*)d_in[24];

    float* out = (float*)d_out;
    float* ws  = (float*)d_ws;

    hipLaunchKernelGGL(k_fused, dim3(192, 3), dim3(128), 0, stream,
                       X, W1, sW1, b1, gam, bet, rmean, rvar, W2, b2, W3, b3, seq, ws, out);
    hipLaunchKernelGGL(k2, dim3(1540), dim3(256), 0, stream,
                       S, ws, sW1, sb1, sW2, sb2, sW3, sb3,
                       c1w, c1b, c2w, c2b, c3w, c3b, out);
}